// Round 8
// baseline (114.383 us; speedup 1.0000x reference)
//
#include <hip/hip_runtime.h>

// Ring-lattice sheaf Laplacian builder: N=50000 nodes, strides 1..16, d=4.
// d_out is FLOAT32, outputs concatenated flat (element offsets):
//   edge_index rows [0, 26.4M) | cols [26.4M, 52.8M)
//   weights         [52.8M, 79.2M)
//   saved_tril_maps [79.2M, 92.0M)
#define NN 50000
#define DG 16
#define EM 800000
#define OFF_COLS 26400000
#define OFF_W    52800000
#define OFF_TRIL 79200000
#define NIDX 6600000

#define NPB 8              // nodes per block (8*32 = 256 threads)
#define NB_N 6250          // 50000/8 node blocks
#define NB_I 25782         // ceil(NIDX/256) idx blocks
#define NB_TOT 32032       // 5*6250 + 782
#define LSTRIDE 544        // LDS floats per node (528 + pad)

typedef unsigned int u32;
typedef float f4v __attribute__((ext_vector_type(4)));

__device__ __forceinline__ void nt_store4(float* p, float a, float b, float c, float d) {
    f4v v = {a, b, c, d};
    __builtin_nontemporal_store(v, (f4v*)p);
}

// ---- bf16 unpack (maps may be bf16-packed) ----
__device__ __forceinline__ void unpack8(uint4 v, float* f) {
    f[0] = __uint_as_float(v.x << 16); f[1] = __uint_as_float(v.x & 0xffff0000u);
    f[2] = __uint_as_float(v.y << 16); f[3] = __uint_as_float(v.y & 0xffff0000u);
    f[4] = __uint_as_float(v.z << 16); f[5] = __uint_as_float(v.z & 0xffff0000u);
    f[6] = __uint_as_float(v.w << 16); f[7] = __uint_as_float(v.w & 0xffff0000u);
}

// rank of node v within sorted({u} U {u +- s mod N, s=1..16}); 33 distinct values.
__device__ __forceinline__ int brank(int u, int v) {
    int a0 = u - DG; if (a0 < 0) a0 += NN;
    if (a0 <= NN - 33) return v - a0;
    int k = a0 + 33 - NN;
    return (v < k) ? v : k + (v - a0);
}
// inverse: node at sorted slot c (0..32, includes u itself)
__device__ __forceinline__ int rinv(int u, int c) {
    int a0 = u - DG; if (a0 < 0) a0 += NN;
    if (a0 <= NN - 33) return a0 + c;
    int k = a0 + 33 - NN;
    return (c < k) ? c : a0 + (c - k);
}

template<bool F32M>
__device__ __forceinline__ void load_map(const void* maps, size_t e, float* F) {
    if (F32M) {
        const float4* p = (const float4*)maps;
        float4 a = p[e*4+0], b = p[e*4+1], c = p[e*4+2], d = p[e*4+3];
        F[0]=a.x; F[1]=a.y; F[2]=a.z; F[3]=a.w;
        F[4]=b.x; F[5]=b.y; F[6]=b.z; F[7]=b.w;
        F[8]=c.x; F[9]=c.y; F[10]=c.z; F[11]=c.w;
        F[12]=d.x; F[13]=d.y; F[14]=d.z; F[15]=d.w;
    } else {
        const uint4* p = (const uint4*)maps;
        unpack8(p[e*2], F); unpack8(p[e*2+1], F + 8);
    }
}

// maps dtype sniff: low-16 halves as bf16 rarely have sane exponents if raw f32
__device__ __forceinline__ int detect_f32(const u32* __restrict__ mw) {
    int sane = 0;
#pragma unroll
    for (int i = 0; i < 32; ++i) {
        u32 ex = (mw[i] >> 7) & 0xFFu;
        sane += (ex >= 0x70u && ex <= 0x87u) ? 1 : 0;
    }
    return (sane < 16) ? 1 : 0;
}

// ---- node-centric: 32 threads per node; thread = one neighbor pair ----
template<bool F32M>
__device__ __forceinline__ void node_body(int blk, int tid, const void* maps,
                                          float* __restrict__ out, float* lds) {
    int k = tid >> 5, s = tid & 31;
    int u = blk * NPB + k;                       // < NN exactly
    int cd = brank(u, u);                        // diag rank (16 for interior)
    int c = s + (s >= cd ? 1 : 0);               // this thread's off-diag rank
    int v = rinv(u, c);
    // pair (bm, am), analytic directed-edge ids + tril index
    int bm = (u < v) ? u : v, am = (u < v) ? v : u;
    int dnw = am - bm;
    size_t eL, eR; int mtr;
    if (dnw <= DG) {                             // no-wrap pair
        eL = (size_t)EM + (size_t)bm * DG + (dnw - 1);   // am->bm (2nd half)
        eR = (size_t)bm * DG + (dnw - 1);                // bm->am (1st half)
        int ex = bm - (NN - DG);
        int corr = (ex > 0) ? ex * (ex + 1) / 2 : 0;
        mtr = 136 + bm * DG + (dnw - 1) - corr;
    } else {                                     // wrap pair
        int dp = NN - dnw;
        eL = (size_t)am * DG + (dp - 1);                 // am->bm (1st half)
        eR = (size_t)EM + (size_t)am * DG + (dp - 1);    // bm->am (2nd half)
        int ja = am - (NN - DG);
        mtr = ja * (ja + 1) / 2 + bm;
    }
    float L[16], R[16];
    load_map<F32M>(maps, eL, L);
    load_map<F32M>(maps, eR, R);
    float T[16];
#pragma unroll
    for (int x = 0; x < 4; ++x)
#pragma unroll
        for (int y = 0; y < 4; ++y)
            T[x*4+y] = -(L[x]*R[y] + L[4+x]*R[4+y] + L[8+x]*R[8+y] + L[12+x]*R[12+y]);
    // diag contribution: outgoing map u->v (already in registers)
    const float* F = (u == am) ? L : R;
    float P[16];
#pragma unroll
    for (int x = 0; x < 4; ++x)
#pragma unroll
        for (int y = 0; y < 4; ++y)
            P[x*4+y] = F[x]*F[y] + F[4+x]*F[4+y] + F[8+x]*F[8+y] + F[12+x]*F[12+y];
    // fold-reduce: 16 partials across 32 lanes in 16 shuffles (static indices)
#pragma unroll
    for (int st = 0; st < 4; ++st) {
        const int m = 1 << st;
        const int cc2 = 8 >> st;                 // half-count at this level
        bool up = (s & m) != 0;
#pragma unroll
        for (int j = 0; j < 8; ++j) {
            if (j < cc2) {
                float mine  = up ? P[cc2 + j] : P[j];
                float other = up ? P[j] : P[cc2 + j];
                P[j] = mine + __shfl_xor(other, m, 64);
            }
        }
    }
    float dv = P[0] + __shfl_xor(P[0], 16, 64);  // lane l: diag elem e(l), e=bitrev4(l)
    // stage this node's weights-row image in LDS (layout: (x, c*4+y))
    float* nb = lds + k * LSTRIDE;
    if (u == am) {                               // block (u,v) = T
#pragma unroll
        for (int x = 0; x < 4; ++x)
            *(f4v*)(nb + x*132 + c*4) = (f4v){T[x*4], T[x*4+1], T[x*4+2], T[x*4+3]};
        // saved_tril_maps[mtr]: one full 64B line, written once per pair
        float* tp = out + OFF_TRIL + (size_t)mtr * 16;
        nt_store4(tp + 0,  T[0],  T[1],  T[2],  T[3]);
        nt_store4(tp + 4,  T[4],  T[5],  T[6],  T[7]);
        nt_store4(tp + 8,  T[8],  T[9],  T[10], T[11]);
        nt_store4(tp + 12, T[12], T[13], T[14], T[15]);
    } else {                                     // block (u,v) = T^T
#pragma unroll
        for (int x = 0; x < 4; ++x)
            *(f4v*)(nb + x*132 + c*4) = (f4v){T[x], T[4+x], T[8+x], T[12+x]};
    }
    if (s < 16) {                                // diag elem e at (e>>2, cd*4 + (e&3))
        int e = ((s & 1) << 3) | (((s >> 1) & 1) << 2) | (((s >> 2) & 1) << 1) | ((s >> 3) & 1);
        nb[(e >> 2) * 132 + cd * 4 + (e & 3)] = dv;
    }
    __syncthreads();
    // stream 8 nodes x 528 floats = 1056 float4, fully coalesced nt
    float* wbase = out + OFF_W + (size_t)blk * (NPB * 528);
#pragma unroll
    for (int i = 0; i < 5; ++i) {
        int id = i * 256 + tid;
        if (id < 1056) {
            int n2 = id / 132, j = id - n2 * 132;
            f4v val = *(f4v*)(lds + n2 * LSTRIDE + j * 4);
            __builtin_nontemporal_store(val, (f4v*)(wbase + (size_t)id * 4));
        }
    }
}

// ---- idx: edge_index rows/cols, pure function of output position ----
__device__ __forceinline__ void idx_body(int t, float* __restrict__ out) {
    int u = t / 132;
    int q = t - u * 132;
    int i = q / 33;
    int bb = q - i * 33;
    int v = rinv(u, bb);
    float rf = (float)(u * 4 + i);
    float c0 = (float)(v * 4);
    nt_store4(out + (size_t)t*4,            rf, rf,       rf,       rf);
    nt_store4(out + OFF_COLS + (size_t)t*4, c0, c0 + 1.f, c0 + 2.f, c0 + 3.f);
}

__global__ void __launch_bounds__(256) k_fused(const void* __restrict__ maps,
                                               float* __restrict__ out) {
    __shared__ float lds[NPB * LSTRIDE];
    int blk = blockIdx.x;
    // interleave: node blocks every 5th slot, idx blocks fill the rest,
    // so read-heavy and write-only blocks co-reside on every CU throughout
    if (blk < 31250 && (blk % 5) == 0) {
        int nid = blk / 5;
        // chunked node mapping: all nid with same (nid&7) share a hardware XCD
        // (dispatch stride 5: (5*(8j+g))&7 == (5g)&7, constant in j)
        int g = nid & 7, j = nid >> 3;
        const int q = NB_N >> 3, r = NB_N & 7;   // 781, 2
        int node_blk = (g < r ? g * (q + 1) : r * (q + 1) + (g - r) * q) + j;
        int f3 = detect_f32((const u32*)maps);
        if (f3) node_body<true >(node_blk, threadIdx.x, maps, out, lds);
        else    node_body<false>(node_blk, threadIdx.x, maps, out, lds);
    } else {
        int iid;
        if (blk < 31250) { int q5 = blk / 5, r5 = blk - q5 * 5; iid = q5 * 4 + (r5 - 1); }
        else             { iid = 25000 + (blk - 31250); }
        int t = iid * 256 + threadIdx.x;
        if (t >= NIDX) return;
        idx_body(t, out);
    }
}

extern "C" void kernel_launch(void* const* d_in, const int* in_sizes, int n_in,
                              void* d_out, int out_size, void* d_ws, size_t ws_size,
                              hipStream_t stream) {
    const void* maps = d_in[0];           // index arrays d_in[1..3] not needed
    float* out = (float*)d_out;
    k_fused<<<NB_TOT, 256, 0, stream>>>(maps, out);
}

// Round 9
// 91.933 us; speedup vs baseline: 1.2442x; 1.2442x over previous
//
#include <hip/hip_runtime.h>

// Ring-lattice sheaf Laplacian builder: N=50000 nodes, strides 1..16, d=4.
// d_out is FLOAT32, outputs concatenated flat (element offsets):
//   edge_index rows [0, 26.4M) | cols [26.4M, 52.8M)
//   weights         [52.8M, 79.2M)
//   saved_tril_maps [79.2M, 92.0M)
// Structure (round-6, best=91.7us): phase-separated grid — node blocks first
// (read maps + write weights/tril), then pure-streaming idx blocks. Phase
// separation beats interleaving (rounds 7/8 both regressed ~20us: DRAM
// read<->write turnaround).
#define NN 50000
#define DG 16
#define EM 800000
#define OFF_COLS 26400000
#define OFF_W    52800000
#define OFF_TRIL 79200000
#define NIDX 6600000

#define NPB 8              // nodes per block (8*32 = 256 threads)
#define NB_N 6250          // 50000/8 node blocks
#define NB_I 25782         // ceil(NIDX/256) idx blocks
#define LSTRIDE 544        // LDS floats per node (528 + pad)

typedef unsigned int u32;
typedef float f4v __attribute__((ext_vector_type(4)));

__device__ __forceinline__ void nt_store4(float* p, float a, float b, float c, float d) {
    f4v v = {a, b, c, d};
    __builtin_nontemporal_store(v, (f4v*)p);
}

// ---- bf16 unpack (maps may be bf16-packed) ----
__device__ __forceinline__ void unpack8(uint4 v, float* f) {
    f[0] = __uint_as_float(v.x << 16); f[1] = __uint_as_float(v.x & 0xffff0000u);
    f[2] = __uint_as_float(v.y << 16); f[3] = __uint_as_float(v.y & 0xffff0000u);
    f[4] = __uint_as_float(v.z << 16); f[5] = __uint_as_float(v.z & 0xffff0000u);
    f[6] = __uint_as_float(v.w << 16); f[7] = __uint_as_float(v.w & 0xffff0000u);
}

// rank of node v within sorted({u} U {u +- s mod N, s=1..16}); 33 distinct values.
__device__ __forceinline__ int brank(int u, int v) {
    int a0 = u - DG; if (a0 < 0) a0 += NN;
    if (a0 <= NN - 33) return v - a0;
    int k = a0 + 33 - NN;
    return (v < k) ? v : k + (v - a0);
}

template<bool F32M>
__device__ __forceinline__ void load_map(const void* maps, size_t e, float* F) {
    if (F32M) {
        const float4* p = (const float4*)maps;
        float4 a = p[e*4+0], b = p[e*4+1], c = p[e*4+2], d = p[e*4+3];
        F[0]=a.x; F[1]=a.y; F[2]=a.z; F[3]=a.w;
        F[4]=b.x; F[5]=b.y; F[6]=b.z; F[7]=b.w;
        F[8]=c.x; F[9]=c.y; F[10]=c.z; F[11]=c.w;
        F[12]=d.x; F[13]=d.y; F[14]=d.z; F[15]=d.w;
    } else {
        const uint4* p = (const uint4*)maps;
        unpack8(p[e*2], F); unpack8(p[e*2+1], F + 8);
    }
}

// maps dtype sniff: low-16 halves as bf16 rarely have sane exponents if raw f32
__device__ __forceinline__ int detect_f32(const u32* __restrict__ mw) {
    int sane = 0;
#pragma unroll
    for (int i = 0; i < 32; ++i) {
        u32 ex = (mw[i] >> 7) & 0xFFu;
        sane += (ex >= 0x70u && ex <= 0x87u) ? 1 : 0;
    }
    return (sane < 16) ? 1 : 0;
}

// ---- node-centric: 32 threads per node; thread = one neighbor pair ----
template<bool F32M>
__device__ __forceinline__ void node_body(int blk, int tid, const void* maps,
                                          float* __restrict__ out, float* lds) {
    int k = tid >> 5, s = tid & 31;
    int u = blk * NPB + k;                       // < NN exactly
    int cd = brank(u, u);                        // diag rank (16 for interior)
    int c = s + (s >= cd ? 1 : 0);               // this thread's off-diag rank
    // rank-inverse -> neighbor v
    int a0 = u - DG; if (a0 < 0) a0 += NN;
    int v;
    if (a0 <= NN - 33) v = a0 + c;
    else { int kk = a0 + 33 - NN; v = (c < kk) ? c : a0 + (c - kk); }
    // pair (bm, am), analytic directed-edge ids + tril index
    int bm = (u < v) ? u : v, am = (u < v) ? v : u;
    int dnw = am - bm;
    size_t eL, eR; int mtr;
    if (dnw <= DG) {                             // no-wrap pair
        eL = (size_t)EM + (size_t)bm * DG + (dnw - 1);   // am->bm (2nd half)
        eR = (size_t)bm * DG + (dnw - 1);                // bm->am (1st half)
        int ex = bm - (NN - DG);
        int corr = (ex > 0) ? ex * (ex + 1) / 2 : 0;
        mtr = 136 + bm * DG + (dnw - 1) - corr;
    } else {                                     // wrap pair
        int dp = NN - dnw;
        eL = (size_t)am * DG + (dp - 1);                 // am->bm (1st half)
        eR = (size_t)EM + (size_t)am * DG + (dp - 1);    // bm->am (2nd half)
        int ja = am - (NN - DG);
        mtr = ja * (ja + 1) / 2 + bm;
    }
    float L[16], R[16];
    load_map<F32M>(maps, eL, L);
    load_map<F32M>(maps, eR, R);
    float T[16];
#pragma unroll
    for (int x = 0; x < 4; ++x)
#pragma unroll
        for (int y = 0; y < 4; ++y)
            T[x*4+y] = -(L[x]*R[y] + L[4+x]*R[4+y] + L[8+x]*R[8+y] + L[12+x]*R[12+y]);
    // diag contribution: outgoing map u->v (already in registers)
    const float* F = (u == am) ? L : R;
    float P[16];
#pragma unroll
    for (int x = 0; x < 4; ++x)
#pragma unroll
        for (int y = 0; y < 4; ++y)
            P[x*4+y] = F[x]*F[y] + F[4+x]*F[4+y] + F[8+x]*F[8+y] + F[12+x]*F[12+y];
    // butterfly sum across the node's 32 lanes (stays within half-wave)
#pragma unroll
    for (int msk = 1; msk < 32; msk <<= 1)
#pragma unroll
        for (int j = 0; j < 16; ++j)
            P[j] += __shfl_xor(P[j], msk, 64);
    // stage this node's weights-row image in LDS (layout: (x, c*4+y))
    float* nb = lds + k * LSTRIDE;
    if (u == am) {                               // block (u,v) = T
#pragma unroll
        for (int x = 0; x < 4; ++x)
            *(f4v*)(nb + x*132 + c*4) = (f4v){T[x*4], T[x*4+1], T[x*4+2], T[x*4+3]};
        // saved_tril_maps[mtr]: one full 64B line, written once per pair
        float* tp = out + OFF_TRIL + (size_t)mtr * 16;
        nt_store4(tp + 0,  T[0],  T[1],  T[2],  T[3]);
        nt_store4(tp + 4,  T[4],  T[5],  T[6],  T[7]);
        nt_store4(tp + 8,  T[8],  T[9],  T[10], T[11]);
        nt_store4(tp + 12, T[12], T[13], T[14], T[15]);
    } else {                                     // block (u,v) = T^T
#pragma unroll
        for (int x = 0; x < 4; ++x)
            *(f4v*)(nb + x*132 + c*4) = (f4v){T[x], T[4+x], T[8+x], T[12+x]};
    }
    if (s == 0) {                                // diag block at rank cd
#pragma unroll
        for (int x = 0; x < 4; ++x)
            *(f4v*)(nb + x*132 + cd*4) = (f4v){P[x*4], P[x*4+1], P[x*4+2], P[x*4+3]};
    }
    __syncthreads();
    // stream 8 nodes x 528 floats = 1056 float4, fully coalesced nt
    float* wbase = out + OFF_W + (size_t)blk * (NPB * 528);
#pragma unroll
    for (int i = 0; i < 5; ++i) {
        int id = i * 256 + tid;
        if (id < 1056) {
            int n2 = id / 132, j = id - n2 * 132;
            f4v val = *(f4v*)(lds + n2 * LSTRIDE + j * 4);
            __builtin_nontemporal_store(val, (f4v*)(wbase + (size_t)id * 4));
        }
    }
}

// ---- idx: edge_index rows/cols, pure function of output position ----
__device__ __forceinline__ void idx_body(int t, float* __restrict__ out) {
    int u = t / 132;
    int q = t - u * 132;
    int i = q / 33;
    int bb = q - i * 33;
    int a0 = u - DG; if (a0 < 0) a0 += NN;
    int v;
    if (a0 <= NN - 33) v = a0 + bb;
    else { int k = a0 + 33 - NN; v = (bb < k) ? bb : a0 + (bb - k); }
    float rf = (float)(u * 4 + i);
    float c0 = (float)(v * 4);
    nt_store4(out + (size_t)t*4,            rf, rf,       rf,       rf);
    nt_store4(out + OFF_COLS + (size_t)t*4, c0, c0 + 1.f, c0 + 2.f, c0 + 3.f);
}

__global__ void __launch_bounds__(256) k_fused(const void* __restrict__ maps,
                                               float* __restrict__ out) {
    __shared__ float lds[NPB * LSTRIDE];
    int blk = blockIdx.x;
    if (blk < NB_N) {
        // bijective chunked XCD swizzle (NB_N = 8*781 + 2)
        int xcd = blk & 7, i = blk >> 3;
        const int q = NB_N >> 3, r = NB_N & 7;
        int nb = (xcd < r ? xcd * (q + 1) : r * (q + 1) + (xcd - r) * q) + i;
        int f3 = detect_f32((const u32*)maps);
        if (f3) node_body<true >(nb, threadIdx.x, maps, out, lds);
        else    node_body<false>(nb, threadIdx.x, maps, out, lds);
    } else {
        int t = (blk - NB_N) * 256 + threadIdx.x;
        if (t >= NIDX) return;
        idx_body(t, out);
    }
}

extern "C" void kernel_launch(void* const* d_in, const int* in_sizes, int n_in,
                              void* d_out, int out_size, void* d_ws, size_t ws_size,
                              hipStream_t stream) {
    const void* maps = d_in[0];           // index arrays d_in[1..3] not needed
    float* out = (float*)d_out;
    k_fused<<<NB_N + NB_I, 256, 0, stream>>>(maps, out);
}